// Round 8
// baseline (294.117 us; speedup 1.0000x reference)
//
#include <hip/hip_runtime.h>
#include <hip/hip_cooperative_groups.h>
namespace cg = cooperative_groups;

// Problem constants
constexpr int N_AG = 4096;
constexpr int M_CL = 256;
constexpr int KD   = 32;
constexpr float WEPS = 1e-6f;

// ws layout (floats). Records now 512 x (m,half): [S2(1024)|S1(32)|Z|count|pad]
constexpr int PART_STRIDE = 1088;
constexpr int VT_OFF = M_CL * 2 * PART_STRIDE;   // 557056 : vT (32 x 4096) k-major
constexpr int WT_OFF = VT_OFF + N_AG * KD;       // Wt (256 x 4096) masked

typedef __attribute__((ext_vector_type(8))) short short8;
typedef __attribute__((ext_vector_type(4))) float f32x4;

__device__ __forceinline__ float rlane(float x, int l) {
    return __int_as_float(__builtin_amdgcn_readlane(__float_as_int(x), l));
}
__device__ __forceinline__ short8 mk8(unsigned a, unsigned b, unsigned c, unsigned d) {
    union { unsigned u[4]; short8 s; } x;
    x.u[0] = a; x.u[1] = b; x.u[2] = c; x.u[3] = d;
    return x.s;
}

// Shared-memory overlays per phase (union -> max 25.2 KB -> 2 blocks/CU fits)
struct SmemA { float res8[32][8]; float tb[32][33]; };
struct SmemB { float swbuf[2048]; float sred[4096]; float red[256]; float s1buf[32]; };
struct SmemC { float omg[32 * 33]; float vbar[32]; float red[256]; };
union SmemU { SmemA a; SmemB b; SmemC c; };

// ---------------------------------------------------------------------------
// GJ, two independent chains per wave (ILP), compile-time J (static reg idx —
// R4 lesson: dynamic col[j] forces scratch).
// ---------------------------------------------------------------------------
template<int J>
struct GJ2 {
    static __device__ __forceinline__ void run(float (&ca)[32], float (&cb)[32]) {
        const float pa = rlane(ca[J], J);
        const float pb = rlane(cb[J], J);
        const float ia = 1.0f / pa;
        const float ib = 1.0f / pb;
        ca[J] *= ia;
        cb[J] *= ib;
        #pragma unroll
        for (int i = 0; i < 32; ++i) {
            if (i == J) continue;
            const float fa = rlane(ca[i], J);
            const float fb = rlane(cb[i], J);
            ca[i] = fmaf(-fa, ca[J], ca[i]);
            cb[i] = fmaf(-fb, cb[J], cb[i]);
        }
        GJ2<J + 1>::run(ca, cb);
    }
};
template<> struct GJ2<32> {
    static __device__ __forceinline__ void run(float (&)[32], float (&)[32]) {}
};

// ---------------------------------------------------------------------------
// Phase A (512 blocks): solve 8 matrices/block -> vT; transpose+mask 2 W tiles
// ---------------------------------------------------------------------------
__device__ __forceinline__ void phaseA(int bid, int t,
        const float* __restrict__ oc, const float* __restrict__ mu,
        const float* __restrict__ W,
        float* __restrict__ vT, float* __restrict__ Wt, SmemA& s) {
    const int lane = t & 63;
    const int wv   = t >> 6;
    const int idx0 = bid * 8;
    const int ia_  = idx0 + 2 * wv;
    const int ib_  = ia_ + 1;
    const int c = (lane < 32) ? lane : 32;

    float ca[32], cb[32];
    #pragma unroll
    for (int i = 0; i < 32; ++i) {
        ca[i] = (c < 32) ? oc[ia_ * 1024 + i * 32 + c] : mu[ia_ * 32 + i];
        cb[i] = (c < 32) ? oc[ib_ * 1024 + i * 32 + c] : mu[ib_ * 32 + i];
    }

    GJ2<0>::run(ca, cb);

    float ra = 0.0f, rb = 0.0f;
    #pragma unroll
    for (int i = 0; i < 32; ++i) {
        const float xa = rlane(ca[i], 32);
        const float xb = rlane(cb[i], 32);
        if (lane == i) { ra = xa; rb = xb; }
    }
    if (lane < 32) {
        s.res8[lane][2 * wv]     = ra;
        s.res8[lane][2 * wv + 1] = rb;
    }
    __syncthreads();
    {
        const int k = t >> 3, j = t & 7;
        vT[(size_t)k * 4096 + idx0 + j] = s.res8[k][j];
    }

    const int x = t & 31, y = t >> 5;
    #pragma unroll
    for (int rep = 0; rep < 2; ++rep) {
        const int tile = bid * 2 + rep;
        const int n0 = (tile & 127) * 32;
        const int m0 = (tile >> 7) * 32;
        __syncthreads();
        #pragma unroll
        for (int r = 0; r < 4; ++r) {
            const int n = y + 8 * r;
            const float w = W[(size_t)(n0 + n) * 256 + m0 + x];
            s.tb[n][x] = (w >= WEPS) ? w : 0.0f;
        }
        __syncthreads();
        #pragma unroll
        for (int r = 0; r < 4; ++r) {
            const int mm = y + 8 * r;
            Wt[(size_t)(m0 + mm) * 4096 + n0 + x] = s.tb[x][mm];
        }
    }
}

// ---------------------------------------------------------------------------
// Phase B (512 blocks, task = (m, half of n)): registers-only MFMA moments.
// Numerics identical to R7 (passed, absmax 0.5): u = sqrt(w)*v, hi/lo bf16
// split, S2 ~= Hh^T Hh + M + M^T with M = Hh^T Hl.
// ---------------------------------------------------------------------------
__device__ __forceinline__ void phaseB(int task, int t,
        const float* __restrict__ Wt, const float* __restrict__ vT,
        float* __restrict__ wsout, SmemB& s) {
    const int m = task >> 1;
    const int h = task & 1;
    const int lane = t & 63;
    const int wv   = t >> 6;

    const float* wrow = Wt + (size_t)m * 4096 + h * 2048;
    float zacc = 0.0f, cacc = 0.0f;
    #pragma unroll
    for (int i = 0; i < 2; ++i) {
        const float4 w4 = reinterpret_cast<const float4*>(wrow)[t + 256 * i];
        zacc += w4.x + w4.y + w4.z + w4.w;
        cacc += (w4.x >= WEPS ? 1.f : 0.f) + (w4.y >= WEPS ? 1.f : 0.f)
              + (w4.z >= WEPS ? 1.f : 0.f) + (w4.w >= WEPS ? 1.f : 0.f);
        reinterpret_cast<float4*>(s.swbuf)[t + 256 * i] =
            make_float4(sqrtf(w4.x), sqrtf(w4.y), sqrtf(w4.z), sqrtf(w4.w));
    }
    if (t < 32) s.s1buf[t] = 0.0f;
    __syncthreads();

    const int a = lane & 15;
    const int g = lane >> 4;
    const int nl = wv * 512 + g * 8;

    const float4* pa4 = reinterpret_cast<const float4*>(vT + (size_t)a * 4096 + h * 2048 + nl);
    const float4* pb4 = reinterpret_cast<const float4*>(vT + (size_t)(a + 16) * 4096 + h * 2048 + nl);

    f32x4 Chh[4], Chl[4];
    #pragma unroll
    for (int q = 0; q < 4; ++q) {
        Chh[q] = (f32x4){0.f, 0.f, 0.f, 0.f};
        Chl[q] = (f32x4){0.f, 0.f, 0.f, 0.f};
    }
    float s1a = 0.0f, s1b = 0.0f;

    #pragma unroll 2
    for (int ch = 0; ch < 16; ++ch) {
        const float4 va0 = pa4[ch * 8];
        const float4 va1 = pa4[ch * 8 + 1];
        const float4 vb0 = pb4[ch * 8];
        const float4 vb1 = pb4[ch * 8 + 1];
        const float4 s0  = *reinterpret_cast<const float4*>(&s.swbuf[nl + ch * 32]);
        const float4 s1v = *reinterpret_cast<const float4*>(&s.swbuf[nl + ch * 32 + 4]);

        const float ua0 = va0.x * s0.x,  ua1 = va0.y * s0.y;
        const float ua2 = va0.z * s0.z,  ua3 = va0.w * s0.w;
        const float ua4 = va1.x * s1v.x, ua5 = va1.y * s1v.y;
        const float ua6 = va1.z * s1v.z, ua7 = va1.w * s1v.w;
        const float ub0 = vb0.x * s0.x,  ub1 = vb0.y * s0.y;
        const float ub2 = vb0.z * s0.z,  ub3 = vb0.w * s0.w;
        const float ub4 = vb1.x * s1v.x, ub5 = vb1.y * s1v.y;
        const float ub6 = vb1.z * s1v.z, ub7 = vb1.w * s1v.w;

        s1a += s0.x*ua0 + s0.y*ua1 + s0.z*ua2 + s0.w*ua3
             + s1v.x*ua4 + s1v.y*ua5 + s1v.z*ua6 + s1v.w*ua7;
        s1b += s0.x*ub0 + s0.y*ub1 + s0.z*ub2 + s0.w*ub3
             + s1v.x*ub4 + s1v.y*ub5 + s1v.z*ub6 + s1v.w*ub7;

        #define BITS(u) __float_as_uint(u)
        #define LO(u)  ((u) - __uint_as_float(BITS(u) & 0xFFFF0000u))
        const short8 h0 = mk8(
            __builtin_amdgcn_perm(BITS(ua1), BITS(ua0), 0x07060302u),
            __builtin_amdgcn_perm(BITS(ua3), BITS(ua2), 0x07060302u),
            __builtin_amdgcn_perm(BITS(ua5), BITS(ua4), 0x07060302u),
            __builtin_amdgcn_perm(BITS(ua7), BITS(ua6), 0x07060302u));
        const short8 h1 = mk8(
            __builtin_amdgcn_perm(BITS(ub1), BITS(ub0), 0x07060302u),
            __builtin_amdgcn_perm(BITS(ub3), BITS(ub2), 0x07060302u),
            __builtin_amdgcn_perm(BITS(ub5), BITS(ub4), 0x07060302u),
            __builtin_amdgcn_perm(BITS(ub7), BITS(ub6), 0x07060302u));
        const float la0 = LO(ua0), la1 = LO(ua1), la2 = LO(ua2), la3 = LO(ua3);
        const float la4 = LO(ua4), la5 = LO(ua5), la6 = LO(ua6), la7 = LO(ua7);
        const float lb0 = LO(ub0), lb1 = LO(ub1), lb2 = LO(ub2), lb3 = LO(ub3);
        const float lb4 = LO(ub4), lb5 = LO(ub5), lb6 = LO(ub6), lb7 = LO(ub7);
        const short8 l0 = mk8(
            __builtin_amdgcn_perm(BITS(la1), BITS(la0), 0x07060302u),
            __builtin_amdgcn_perm(BITS(la3), BITS(la2), 0x07060302u),
            __builtin_amdgcn_perm(BITS(la5), BITS(la4), 0x07060302u),
            __builtin_amdgcn_perm(BITS(la7), BITS(la6), 0x07060302u));
        const short8 l1 = mk8(
            __builtin_amdgcn_perm(BITS(lb1), BITS(lb0), 0x07060302u),
            __builtin_amdgcn_perm(BITS(lb3), BITS(lb2), 0x07060302u),
            __builtin_amdgcn_perm(BITS(lb5), BITS(lb4), 0x07060302u),
            __builtin_amdgcn_perm(BITS(lb7), BITS(lb6), 0x07060302u));
        #undef BITS
        #undef LO

        Chh[0] = __builtin_amdgcn_mfma_f32_16x16x32_bf16(h0, h0, Chh[0], 0, 0, 0);
        Chh[1] = __builtin_amdgcn_mfma_f32_16x16x32_bf16(h0, h1, Chh[1], 0, 0, 0);
        Chh[2] = __builtin_amdgcn_mfma_f32_16x16x32_bf16(h1, h0, Chh[2], 0, 0, 0);
        Chh[3] = __builtin_amdgcn_mfma_f32_16x16x32_bf16(h1, h1, Chh[3], 0, 0, 0);
        Chl[0] = __builtin_amdgcn_mfma_f32_16x16x32_bf16(h0, l0, Chl[0], 0, 0, 0);
        Chl[1] = __builtin_amdgcn_mfma_f32_16x16x32_bf16(h0, l1, Chl[1], 0, 0, 0);
        Chl[2] = __builtin_amdgcn_mfma_f32_16x16x32_bf16(h1, l0, Chl[2], 0, 0, 0);
        Chl[3] = __builtin_amdgcn_mfma_f32_16x16x32_bf16(h1, l1, Chl[3], 0, 0, 0);
    }

    s1a += __shfl_xor(s1a, 16); s1a += __shfl_xor(s1a, 32);
    s1b += __shfl_xor(s1b, 16); s1b += __shfl_xor(s1b, 32);
    if (lane < 16) {
        atomicAdd(&s.s1buf[a], s1a);
        atomicAdd(&s.s1buf[a + 16], s1b);
    }

    float* rw = &s.sred[wv * 1024];
    #pragma unroll
    for (int q = 0; q < 4; ++q) {
        const int I = q >> 1, J = q & 1;
        #pragma unroll
        for (int r = 0; r < 4; ++r) {
            const int ar = I * 16 + (lane >> 4) * 4 + r;
            const int br = J * 16 + (lane & 15);
            rw[ar * 32 + br] = Chh[q][r] + Chl[q][r];
        }
    }
    __syncthreads();
    #pragma unroll
    for (int q = 0; q < 4; ++q) {
        const int I = q >> 1, J = q & 1;
        #pragma unroll
        for (int r = 0; r < 4; ++r) {
            const int ar = I * 16 + (lane >> 4) * 4 + r;
            const int br = J * 16 + (lane & 15);
            rw[br * 32 + ar] += Chl[q][r];
        }
    }
    __syncthreads();

    const size_t base = (size_t)task * PART_STRIDE;
    float o0 = 0.f, o1 = 0.f, o2 = 0.f, o3 = 0.f;
    #pragma unroll
    for (int ww = 0; ww < 4; ++ww) {
        const float4 x = *reinterpret_cast<const float4*>(&s.sred[ww * 1024 + t * 4]);
        o0 += x.x; o1 += x.y; o2 += x.z; o3 += x.w;
    }
    *reinterpret_cast<float4*>(&wsout[base + t * 4]) = make_float4(o0, o1, o2, o3);

    s.red[t] = zacc; __syncthreads();
    #pragma unroll
    for (int st = 128; st > 0; st >>= 1) {
        if (t < st) s.red[t] += s.red[t + st];
        __syncthreads();
    }
    if (t == 0) wsout[base + 1056] = s.red[0];
    __syncthreads();
    s.red[t] = cacc; __syncthreads();
    #pragma unroll
    for (int st = 128; st > 0; st >>= 1) {
        if (t < st) s.red[t] += s.red[t + st];
        __syncthreads();
    }
    if (t == 0) wsout[base + 1057] = s.red[0];
    if (t < 32) wsout[base + 1024 + t] = s.s1buf[t];
}

// ---------------------------------------------------------------------------
// Phase C (blocks 0..255): G = op^T op; psi = tr(G S2)/Z - vbar^T G vbar
// ---------------------------------------------------------------------------
__device__ __forceinline__ void phaseC(int m, int t,
        const float* __restrict__ op, const float* __restrict__ ws,
        float* __restrict__ out, SmemC& s) {
    #pragma unroll
    for (int i = 0; i < 4; ++i) {
        const int gg = t + 256 * i;
        const int r = gg >> 5, cc = gg & 31;
        s.omg[r * 33 + cc] = op[(size_t)m * 1024 + gg];
    }

    const size_t mb = (size_t)m * 2 * PART_STRIDE;
    float Z = 0.0f, cnt = 0.0f, s1 = 0.0f;
    float s2[4] = {0.f, 0.f, 0.f, 0.f};
    #pragma unroll
    for (int p2 = 0; p2 < 2; ++p2) {
        const size_t bp = mb + (size_t)p2 * PART_STRIDE;
        Z   += ws[bp + 1056];
        cnt += ws[bp + 1057];
        if (t < 32) s1 += ws[bp + 1024 + t];
        const float4 sp = *reinterpret_cast<const float4*>(&ws[bp + t * 4]);
        s2[0] += sp.x; s2[1] += sp.y; s2[2] += sp.z; s2[3] += sp.w;
    }
    const float invZ = 1.0f / fmaxf(Z, 1e-30f);
    if (t < 32) s.vbar[t] = s1 * invZ;
    __syncthreads();

    const int k  = t >> 3;
    const int l0 = (t & 7) * 4;
    float G[4] = {0.f, 0.f, 0.f, 0.f};
    #pragma unroll
    for (int i = 0; i < 32; ++i) {
        const float ok = s.omg[i * 33 + k];
        #pragma unroll
        for (int q = 0; q < 4; ++q) G[q] = fmaf(ok, s.omg[i * 33 + l0 + q], G[q]);
    }

    const float vk = s.vbar[k];
    float val = 0.0f;
    #pragma unroll
    for (int q = 0; q < 4; ++q)
        val += G[q] * (s2[q] * invZ - vk * s.vbar[l0 + q]);

    s.red[t] = val; __syncthreads();
    #pragma unroll
    for (int st = 128; st > 0; st >>= 1) {
        if (t < st) s.red[t] += s.red[t + st];
        __syncthreads();
    }
    if (t == 0) out[m] = (cnt >= 1.5f) ? s.red[0] : 0.0f;
}

// ---------------------------------------------------------------------------
// Fused cooperative kernel: A -> grid.sync -> B -> grid.sync -> C
// grid = 512 x 256 (2 blocks/CU co-resident: LDS 25KB, VGPR<=256 via bound)
// ---------------------------------------------------------------------------
__global__ __launch_bounds__(256, 2) void fused_kernel(
        const float* __restrict__ W, const float* __restrict__ mu,
        const float* __restrict__ oc, const float* __restrict__ op,
        float* __restrict__ out, float* __restrict__ ws) {
    __shared__ SmemU smem;
    cg::grid_group grid = cg::this_grid();
    const int bid = blockIdx.x;
    const int t = threadIdx.x;
    float* vT = ws + VT_OFF;
    float* Wt = ws + WT_OFF;

    phaseA(bid, t, oc, mu, W, vT, Wt, smem.a);
    __threadfence();
    grid.sync();
    phaseB(bid, t, Wt, vT, ws, smem.b);
    __threadfence();
    grid.sync();
    if (bid < 256) phaseC(bid, t, op, ws, out, smem.c);
}

// Fallback (non-cooperative) wrappers, same phase bodies
__global__ __launch_bounds__(256, 2) void kA(const float* __restrict__ oc,
        const float* __restrict__ mu, const float* __restrict__ W,
        float* __restrict__ vT, float* __restrict__ Wt) {
    __shared__ SmemA s;
    phaseA(blockIdx.x, threadIdx.x, oc, mu, W, vT, Wt, s);
}
__global__ __launch_bounds__(256, 2) void kB(const float* __restrict__ Wt,
        const float* __restrict__ vT, float* __restrict__ ws) {
    __shared__ SmemB s;
    phaseB(blockIdx.x, threadIdx.x, Wt, vT, ws, s);
}
__global__ __launch_bounds__(256) void kC(const float* __restrict__ op,
        const float* __restrict__ ws, float* __restrict__ out) {
    __shared__ SmemC s;
    phaseC(blockIdx.x, threadIdx.x, op, ws, out, s);
}

// ---------------------------------------------------------------------------
extern "C" void kernel_launch(void* const* d_in, const int* in_sizes, int n_in,
                              void* d_out, int out_size, void* d_ws, size_t ws_size,
                              hipStream_t stream) {
    const float* W  = (const float*)d_in[0];  // (4096, 256)
    const float* mu = (const float*)d_in[1];  // (4096, 32)
    const float* oc = (const float*)d_in[2];  // (4096, 32, 32)
    const float* op = (const float*)d_in[3];  // (256, 32, 32)
    float* out = (float*)d_out;               // (256,)
    float* ws  = (float*)d_ws;

    void* kargs[] = { (void*)&W, (void*)&mu, (void*)&oc, (void*)&op,
                      (void*)&out, (void*)&ws };
    hipError_t e = hipLaunchCooperativeKernel(
        reinterpret_cast<void*>(fused_kernel), dim3(512), dim3(256),
        kargs, 0, stream);
    if (e != hipSuccess) {
        // non-cooperative fallback: stream order provides the phase barriers
        kA<<<512, 256, 0, stream>>>(oc, mu, W, ws + VT_OFF, ws + WT_OFF);
        kB<<<512, 256, 0, stream>>>(ws + WT_OFF, ws + VT_OFF, ws);
        kC<<<256, 256, 0, stream>>>(op, ws, out);
    }
}

// Round 9
// 116.505 us; speedup vs baseline: 2.5245x; 2.5245x over previous
//
#include <hip/hip_runtime.h>

// Problem constants (fixed by reference)
constexpr int N_AG = 4096;
constexpr int M_CL = 256;
constexpr int KD   = 32;
constexpr float WEPS = 1e-6f;

// ws layout (floats)
constexpr int PART_STRIDE = 1088;              // [S2(1024) | S1(32) | Z | count | pad]
constexpr int VT_OFF = M_CL * 4 * PART_STRIDE; // vT (32 x 4096) k-major
constexpr int WT_OFF = VT_OFF + N_AG * KD;     // Wt (256 x 4096) masked

typedef __attribute__((ext_vector_type(8))) short short8;   // 8 bf16
typedef __attribute__((ext_vector_type(4))) float f32x4;

__device__ __forceinline__ float rlane(float x, int l) {
    return __int_as_float(__builtin_amdgcn_readlane(__float_as_int(x), l));
}
__device__ __forceinline__ short8 mk8(unsigned a, unsigned b, unsigned c, unsigned d) {
    union { unsigned u[4]; short8 s; } x;
    x.u[0] = a; x.u[1] = b; x.u[2] = c; x.u[3] = d;
    return x.s;
}

// ---------------------------------------------------------------------------
// K1: fused solve + W-transpose.
// ROUND-9: GJ rewritten with NAMED SCALARS (macro-unrolled). Evidence: every
// array-based GJ variant was spilled by the compiler regardless of
// launch_bounds (R4 VGPR=24, R8 fused VGPR=56 < the 64+ live floats two
// chains need) -> scratch-resident readlane chains -> ~50..200us of latency
// stalls (R8: VALUBusy 10.7%, 219us for work whose issue floor is ~23us).
// Named scalars cannot be allocaed, so the register file is guaranteed.
// Two independent chains per wave for ILP; (256,1) -> VGPR budget 512.
// ---------------------------------------------------------------------------
#define ALL32(M) M(0) M(1) M(2) M(3) M(4) M(5) M(6) M(7) \
                 M(8) M(9) M(10) M(11) M(12) M(13) M(14) M(15) \
                 M(16) M(17) M(18) M(19) M(20) M(21) M(22) M(23) \
                 M(24) M(25) M(26) M(27) M(28) M(29) M(30) M(31)

#define DECL(I) float a##I, b##I;
#define LDA(I) a##I = (c < 32) ? oc[ia_ * 1024 + I * 32 + c] : mu[ia_ * 32 + I]; \
               b##I = (c < 32) ? oc[ib_ * 1024 + I * 32 + c] : mu[ib_ * 32 + I];
#define EL(I, J) if constexpr (I != J) { \
    const float fa##I = rlane(a##I, J); a##I = fmaf(-fa##I, a##J, a##I); \
    const float fb##I = rlane(b##I, J); b##I = fmaf(-fb##I, b##J, b##I); }
#define ELALL(J) EL(0,J) EL(1,J) EL(2,J) EL(3,J) EL(4,J) EL(5,J) EL(6,J) EL(7,J) \
                 EL(8,J) EL(9,J) EL(10,J) EL(11,J) EL(12,J) EL(13,J) EL(14,J) EL(15,J) \
                 EL(16,J) EL(17,J) EL(18,J) EL(19,J) EL(20,J) EL(21,J) EL(22,J) EL(23,J) \
                 EL(24,J) EL(25,J) EL(26,J) EL(27,J) EL(28,J) EL(29,J) EL(30,J) EL(31,J)
#define STEP(J) { \
    const float pa = rlane(a##J, J); const float pb = rlane(b##J, J); \
    const float qa = 1.0f / pa;      const float qb = 1.0f / pb; \
    a##J *= qa;                      b##J *= qb; \
    ELALL(J) }
#define OUTP(I) { const float xa = rlane(a##I, 32); const float xb = rlane(b##I, 32); \
    if (lane == I) { ova = xa; ovb = xb; } }

__global__ __launch_bounds__(256, 1) void solve_transpose_kernel(
        const float* __restrict__ oc, const float* __restrict__ mu,
        const float* __restrict__ W,
        float* __restrict__ vT, float* __restrict__ Wt) {
    __shared__ float res8[32][8];
    __shared__ float tb[32][33];

    const int t    = threadIdx.x;
    const int lane = t & 63;
    const int wv   = t >> 6;
    const int idx0 = blockIdx.x * 8;
    const int ia_  = idx0 + 2 * wv;
    const int ib_  = ia_ + 1;
    const int c = (lane < 32) ? lane : 32;

    ALL32(DECL)
    ALL32(LDA)
    ALL32(STEP)

    float ova = 0.0f, ovb = 0.0f;
    ALL32(OUTP)

    if (lane < 32) {
        res8[lane][2 * wv]     = ova;
        res8[lane][2 * wv + 1] = ovb;
    }
    __syncthreads();
    {   // vT[k][idx0+j] : 8 consecutive n's per k-row
        const int k = t >> 3, j = t & 7;
        vT[(size_t)k * 4096 + idx0 + j] = res8[k][j];
    }

    // ---- two 32x32 W transpose tiles (masked) ----
    const int x = t & 31, y = t >> 5;
    #pragma unroll
    for (int rep = 0; rep < 2; ++rep) {
        const int tile = blockIdx.x * 2 + rep;
        const int n0 = (tile & 127) * 32;
        const int m0 = (tile >> 7) * 32;
        __syncthreads();
        #pragma unroll
        for (int r = 0; r < 4; ++r) {
            const int n = y + 8 * r;
            const float w = W[(size_t)(n0 + n) * 256 + m0 + x];
            tb[n][x] = (w >= WEPS) ? w : 0.0f;
        }
        __syncthreads();
        #pragma unroll
        for (int r = 0; r < 4; ++r) {
            const int mm = y + 8 * r;
            Wt[(size_t)(m0 + mm) * 4096 + n0 + x] = tb[x][mm];
        }
    }
}

// ---------------------------------------------------------------------------
// K2: partial weighted moments per (m,p) — registers-only MFMA (R7, passed
// at absmax 0.5). u = sqrt(w)*v; hi/lo bf16 split (RTZ);
// S2 ~= Hh^T Hh + M + M^T with M = Hh^T Hl. Fragments loaded directly from
// k-major vT as 2 float4/row; no LDS staging in the main loop.
// ---------------------------------------------------------------------------
__global__ __launch_bounds__(256, 4) void partial_kernel(const float* __restrict__ Wt,
                                                         const float* __restrict__ vT,
                                                         float* __restrict__ wsout) {
    const int m = blockIdx.x >> 2;
    const int p = blockIdx.x & 3;
    const int t = threadIdx.x;
    const int lane = t & 63;
    const int wv   = t >> 6;

    __shared__ float swbuf[1024];
    __shared__ float sred[4 * 1024];
    __shared__ float red[256];
    __shared__ float s1buf[32];

    const float4 wv4 = reinterpret_cast<const float4*>(Wt + (size_t)m * 4096 + p * 1024)[t];
    const float zacc = wv4.x + wv4.y + wv4.z + wv4.w;
    const float cacc = (wv4.x >= WEPS ? 1.f : 0.f) + (wv4.y >= WEPS ? 1.f : 0.f)
                     + (wv4.z >= WEPS ? 1.f : 0.f) + (wv4.w >= WEPS ? 1.f : 0.f);
    reinterpret_cast<float4*>(swbuf)[t] =
        make_float4(sqrtf(wv4.x), sqrtf(wv4.y), sqrtf(wv4.z), sqrtf(wv4.w));
    if (t < 32) s1buf[t] = 0.0f;
    __syncthreads();

    const int a = lane & 15;
    const int g = lane >> 4;
    const int nl = wv * 256 + g * 8;

    const float4* pa4 = reinterpret_cast<const float4*>(vT + (size_t)a * 4096 + p * 1024 + nl);
    const float4* pb4 = reinterpret_cast<const float4*>(vT + (size_t)(a + 16) * 4096 + p * 1024 + nl);

    f32x4 Chh[4], Chl[4];
    #pragma unroll
    for (int q = 0; q < 4; ++q) {
        Chh[q] = (f32x4){0.f, 0.f, 0.f, 0.f};
        Chl[q] = (f32x4){0.f, 0.f, 0.f, 0.f};
    }
    float s1a = 0.0f, s1b = 0.0f;

    #pragma unroll 2
    for (int ch = 0; ch < 8; ++ch) {
        const float4 va0 = pa4[ch * 8];
        const float4 va1 = pa4[ch * 8 + 1];
        const float4 vb0 = pb4[ch * 8];
        const float4 vb1 = pb4[ch * 8 + 1];
        const float4 s0  = *reinterpret_cast<const float4*>(&swbuf[nl + ch * 32]);
        const float4 s1v = *reinterpret_cast<const float4*>(&swbuf[nl + ch * 32 + 4]);

        const float ua0 = va0.x * s0.x,  ua1 = va0.y * s0.y;
        const float ua2 = va0.z * s0.z,  ua3 = va0.w * s0.w;
        const float ua4 = va1.x * s1v.x, ua5 = va1.y * s1v.y;
        const float ua6 = va1.z * s1v.z, ua7 = va1.w * s1v.w;
        const float ub0 = vb0.x * s0.x,  ub1 = vb0.y * s0.y;
        const float ub2 = vb0.z * s0.z,  ub3 = vb0.w * s0.w;
        const float ub4 = vb1.x * s1v.x, ub5 = vb1.y * s1v.y;
        const float ub6 = vb1.z * s1v.z, ub7 = vb1.w * s1v.w;

        s1a += s0.x*ua0 + s0.y*ua1 + s0.z*ua2 + s0.w*ua3
             + s1v.x*ua4 + s1v.y*ua5 + s1v.z*ua6 + s1v.w*ua7;
        s1b += s0.x*ub0 + s0.y*ub1 + s0.z*ub2 + s0.w*ub3
             + s1v.x*ub4 + s1v.y*ub5 + s1v.z*ub6 + s1v.w*ub7;

        #define BITS(u) __float_as_uint(u)
        #define LOF(u) ((u) - __uint_as_float(BITS(u) & 0xFFFF0000u))
        const short8 h0 = mk8(
            __builtin_amdgcn_perm(BITS(ua1), BITS(ua0), 0x07060302u),
            __builtin_amdgcn_perm(BITS(ua3), BITS(ua2), 0x07060302u),
            __builtin_amdgcn_perm(BITS(ua5), BITS(ua4), 0x07060302u),
            __builtin_amdgcn_perm(BITS(ua7), BITS(ua6), 0x07060302u));
        const short8 h1 = mk8(
            __builtin_amdgcn_perm(BITS(ub1), BITS(ub0), 0x07060302u),
            __builtin_amdgcn_perm(BITS(ub3), BITS(ub2), 0x07060302u),
            __builtin_amdgcn_perm(BITS(ub5), BITS(ub4), 0x07060302u),
            __builtin_amdgcn_perm(BITS(ub7), BITS(ub6), 0x07060302u));
        const float la0 = LOF(ua0), la1 = LOF(ua1), la2 = LOF(ua2), la3 = LOF(ua3);
        const float la4 = LOF(ua4), la5 = LOF(ua5), la6 = LOF(ua6), la7 = LOF(ua7);
        const float lb0 = LOF(ub0), lb1 = LOF(ub1), lb2 = LOF(ub2), lb3 = LOF(ub3);
        const float lb4 = LOF(ub4), lb5 = LOF(ub5), lb6 = LOF(ub6), lb7 = LOF(ub7);
        const short8 l0 = mk8(
            __builtin_amdgcn_perm(BITS(la1), BITS(la0), 0x07060302u),
            __builtin_amdgcn_perm(BITS(la3), BITS(la2), 0x07060302u),
            __builtin_amdgcn_perm(BITS(la5), BITS(la4), 0x07060302u),
            __builtin_amdgcn_perm(BITS(la7), BITS(la6), 0x07060302u));
        const short8 l1 = mk8(
            __builtin_amdgcn_perm(BITS(lb1), BITS(lb0), 0x07060302u),
            __builtin_amdgcn_perm(BITS(lb3), BITS(lb2), 0x07060302u),
            __builtin_amdgcn_perm(BITS(lb5), BITS(lb4), 0x07060302u),
            __builtin_amdgcn_perm(BITS(lb7), BITS(lb6), 0x07060302u));
        #undef BITS
        #undef LOF

        Chh[0] = __builtin_amdgcn_mfma_f32_16x16x32_bf16(h0, h0, Chh[0], 0, 0, 0);
        Chh[1] = __builtin_amdgcn_mfma_f32_16x16x32_bf16(h0, h1, Chh[1], 0, 0, 0);
        Chh[2] = __builtin_amdgcn_mfma_f32_16x16x32_bf16(h1, h0, Chh[2], 0, 0, 0);
        Chh[3] = __builtin_amdgcn_mfma_f32_16x16x32_bf16(h1, h1, Chh[3], 0, 0, 0);
        Chl[0] = __builtin_amdgcn_mfma_f32_16x16x32_bf16(h0, l0, Chl[0], 0, 0, 0);
        Chl[1] = __builtin_amdgcn_mfma_f32_16x16x32_bf16(h0, l1, Chl[1], 0, 0, 0);
        Chl[2] = __builtin_amdgcn_mfma_f32_16x16x32_bf16(h1, l0, Chl[2], 0, 0, 0);
        Chl[3] = __builtin_amdgcn_mfma_f32_16x16x32_bf16(h1, l1, Chl[3], 0, 0, 0);
    }

    s1a += __shfl_xor(s1a, 16); s1a += __shfl_xor(s1a, 32);
    s1b += __shfl_xor(s1b, 16); s1b += __shfl_xor(s1b, 32);
    if (lane < 16) {
        atomicAdd(&s1buf[a], s1a);
        atomicAdd(&s1buf[a + 16], s1b);
    }

    float* rw = &sred[wv * 1024];
    #pragma unroll
    for (int q = 0; q < 4; ++q) {
        const int I = q >> 1, J = q & 1;
        #pragma unroll
        for (int r = 0; r < 4; ++r) {
            const int ar = I * 16 + (lane >> 4) * 4 + r;
            const int br = J * 16 + (lane & 15);
            rw[ar * 32 + br] = Chh[q][r] + Chl[q][r];
        }
    }
    __syncthreads();
    #pragma unroll
    for (int q = 0; q < 4; ++q) {
        const int I = q >> 1, J = q & 1;
        #pragma unroll
        for (int r = 0; r < 4; ++r) {
            const int ar = I * 16 + (lane >> 4) * 4 + r;
            const int br = J * 16 + (lane & 15);
            rw[br * 32 + ar] += Chl[q][r];
        }
    }
    __syncthreads();

    const size_t base = (size_t)(m * 4 + p) * PART_STRIDE;
    float o0 = 0.f, o1 = 0.f, o2 = 0.f, o3 = 0.f;
    #pragma unroll
    for (int ww = 0; ww < 4; ++ww) {
        const float4 x = *reinterpret_cast<const float4*>(&sred[ww * 1024 + t * 4]);
        o0 += x.x; o1 += x.y; o2 += x.z; o3 += x.w;
    }
    *reinterpret_cast<float4*>(&wsout[base + t * 4]) = make_float4(o0, o1, o2, o3);

    red[t] = zacc; __syncthreads();
    #pragma unroll
    for (int s = 128; s > 0; s >>= 1) {
        if (t < s) red[t] += red[t + s];
        __syncthreads();
    }
    if (t == 0) wsout[base + 1056] = red[0];
    __syncthreads();
    red[t] = cacc; __syncthreads();
    #pragma unroll
    for (int s = 128; s > 0; s >>= 1) {
        if (t < s) red[t] += red[t + s];
        __syncthreads();
    }
    if (t == 0) wsout[base + 1057] = red[0];
    if (t < 32) wsout[base + 1024 + t] = s1buf[t];
}

// ---------------------------------------------------------------------------
// K3: combine. One block per m.
// ---------------------------------------------------------------------------
__global__ __launch_bounds__(256) void combine_kernel(const float* __restrict__ op,
                                                      const float* __restrict__ ws,
                                                      float* __restrict__ out) {
    const int m = blockIdx.x;
    const int t = threadIdx.x;

    __shared__ float omg[32 * 33];
    __shared__ float vbar[32];
    __shared__ float red[256];

    #pragma unroll
    for (int i = 0; i < 4; ++i) {
        const int g = t + 256 * i;
        const int r = g >> 5, cc = g & 31;
        omg[r * 33 + cc] = op[(size_t)m * 1024 + g];
    }

    const size_t mb = (size_t)m * 4 * PART_STRIDE;
    float Z = 0.0f, cnt = 0.0f, s1 = 0.0f;
    float s2[4] = {0.f, 0.f, 0.f, 0.f};
    #pragma unroll
    for (int p2 = 0; p2 < 4; ++p2) {
        const size_t bp = mb + (size_t)p2 * PART_STRIDE;
        Z   += ws[bp + 1056];
        cnt += ws[bp + 1057];
        if (t < 32) s1 += ws[bp + 1024 + t];
        const float4 sp = *reinterpret_cast<const float4*>(&ws[bp + t * 4]);
        s2[0] += sp.x; s2[1] += sp.y; s2[2] += sp.z; s2[3] += sp.w;
    }
    const float invZ = 1.0f / fmaxf(Z, 1e-30f);
    if (t < 32) vbar[t] = s1 * invZ;
    __syncthreads();

    const int k  = t >> 3;
    const int l0 = (t & 7) * 4;
    float G[4] = {0.f, 0.f, 0.f, 0.f};
    #pragma unroll
    for (int i = 0; i < 32; ++i) {
        const float ok = omg[i * 33 + k];
        #pragma unroll
        for (int q = 0; q < 4; ++q) G[q] = fmaf(ok, omg[i * 33 + l0 + q], G[q]);
    }

    const float vk = vbar[k];
    float val = 0.0f;
    #pragma unroll
    for (int q = 0; q < 4; ++q)
        val += G[q] * (s2[q] * invZ - vk * vbar[l0 + q]);

    red[t] = val; __syncthreads();
    #pragma unroll
    for (int s = 128; s > 0; s >>= 1) {
        if (t < s) red[t] += red[t + s];
        __syncthreads();
    }
    if (t == 0) out[m] = (cnt >= 1.5f) ? red[0] : 0.0f;
}

// ---------------------------------------------------------------------------
extern "C" void kernel_launch(void* const* d_in, const int* in_sizes, int n_in,
                              void* d_out, int out_size, void* d_ws, size_t ws_size,
                              hipStream_t stream) {
    const float* W  = (const float*)d_in[0];  // (4096, 256)
    const float* mu = (const float*)d_in[1];  // (4096, 32)
    const float* oc = (const float*)d_in[2];  // (4096, 32, 32)
    const float* op = (const float*)d_in[3];  // (256, 32, 32)
    float* out = (float*)d_out;               // (256,)
    float* ws  = (float*)d_ws;

    solve_transpose_kernel<<<512, 256, 0, stream>>>(oc, mu, W, ws + VT_OFF, ws + WT_OFF);
    partial_kernel<<<1024, 256, 0, stream>>>(ws + WT_OFF, ws + VT_OFF, ws);
    combine_kernel<<<256, 256, 0, stream>>>(op, ws, out);
}